// Round 2
// baseline (349.093 us; speedup 1.0000x reference)
//
#include <hip/hip_runtime.h>
#include <stdint.h>

#define HW        (1024 * 1024)
#define KIDS      64
#define NCANDS    16
#define BCC       76          /* B*C = 4*19 */
#define EPSF      1e-6f
#define MARGINF   1.0f
#define SENTINEL  0x7FFFFFFF
#define SEGB      256         /* k_seg grid: 4096 pixels per block */

// JAX PRNG variant: 1 = threefry_partitionable (default since JAX 0.5.0).
#define JAX_PARTITIONABLE 1

__device__ __forceinline__ uint32_t rotl32(uint32_t v, int r) {
    return (v << r) | (v >> (32 - r));
}

// Threefry-2x32, 20 rounds — exact JAX schedule.
__device__ void threefry2x32(uint32_t k0, uint32_t k1, uint32_t x0, uint32_t x1,
                             uint32_t* o0, uint32_t* o1) {
    const uint32_t ks2 = k0 ^ k1 ^ 0x1BD11BDAu;
    const int R0[4] = {13, 15, 26, 6};
    const int R1[4] = {17, 29, 16, 24};
    x0 += k0; x1 += k1;
#pragma unroll
    for (int i = 0; i < 4; i++) { x0 += x1; x1 = rotl32(x1, R0[i]); x1 ^= x0; }
    x0 += k1; x1 += ks2 + 1u;
#pragma unroll
    for (int i = 0; i < 4; i++) { x0 += x1; x1 = rotl32(x1, R1[i]); x1 ^= x0; }
    x0 += ks2; x1 += k0 + 2u;
#pragma unroll
    for (int i = 0; i < 4; i++) { x0 += x1; x1 = rotl32(x1, R0[i]); x1 ^= x0; }
    x0 += k0; x1 += k1 + 3u;
#pragma unroll
    for (int i = 0; i < 4; i++) { x0 += x1; x1 = rotl32(x1, R1[i]); x1 ^= x0; }
    x0 += k1; x1 += ks2 + 4u;
#pragma unroll
    for (int i = 0; i < 4; i++) { x0 += x1; x1 = rotl32(x1, R0[i]); x1 ^= x0; }
    x0 += ks2; x1 += k0 + 5u;
    *o0 = x0; *o1 = x1;
}

// lower_bits[j] for j in [0, 1024): 32-bit random word whose low 20 bits are
// cand[j/16][j%16]. key(1) -> (0,1); k2 = split(key)[1].
__device__ uint32_t jax_cand_bits(uint32_t j) {
#if JAX_PARTITIONABLE
    uint32_t k2a, k2b;
    threefry2x32(0u, 1u, 0u, 1u, &k2a, &k2b);      // constant-folds at -O3
    uint32_t b1, b2;
    threefry2x32(k2a, k2b, 0u, j, &b1, &b2);       // iota_2x32 counts (0, j)
    return b1 ^ b2;                                // 32-bit path xors halves
#else
    uint32_t a0, a1, b0, b1;
    threefry2x32(0u, 1u, 0u, 2u, &a0, &a1);
    threefry2x32(0u, 1u, 1u, 3u, &b0, &b1);
    uint32_t k2a = a1, k2b = b1;
    uint32_t r0, r1;
    if (j < 512u) { threefry2x32(k2a, k2b, j, j + 512u, &r0, &r1); return r0; }
    else          { threefry2x32(k2a, k2b, j - 512u, j, &r0, &r1); return r1; }
#endif
}

// pair-merge: two smallest of the union of two (lo,hi) sorted pairs
__device__ __forceinline__ void pmerge(int& lo, int& hi, int alo, int ahi) {
    const int nlo = min(lo, alo);
    const int nhi = min(max(lo, alo), min(hi, ahi));
    lo = nlo; hi = nhi;
}

// One pass over the mask: per-block LDS (min1, min2) per id -> per-block
// partials. Block 0 also zero-inits the fused-finalize accumulators (safe:
// stream order guarantees k_seg retires before k_triplet starts).
__global__ void k_seg(const int* __restrict__ mask, int2* __restrict__ part,
                      float* g_total, int* g_cnt, int* g_done) {
    __shared__ int m1[KIDS], m2[KIDS];
    const int t = threadIdx.x;
    if (blockIdx.x == 0 && t == 0) { *g_total = 0.0f; *g_cnt = 0; *g_done = 0; }
    if (t < KIDS) { m1[t] = SENTINEL; m2[t] = SENTINEL; }
    __syncthreads();

    const int4* m4 = (const int4*)mask;
    const int base4 = blockIdx.x * 1024;   // 4096 pixels per block / 4
    int4 v[4];
#pragma unroll
    for (int c = 0; c < 4; c++) v[c] = m4[base4 + c * 256 + t];

#pragma unroll
    for (int c = 0; c < 4; c++) {
        const int pix0 = (base4 + c * 256 + t) * 4;
        const int ids[4] = {v[c].x, v[c].y, v[c].z, v[c].w};
#pragma unroll
        for (int j = 0; j < 4; j++) atomicMin(&m1[ids[j]], pix0 + j);
    }
    __syncthreads();
#pragma unroll
    for (int c = 0; c < 4; c++) {
        const int pix0 = (base4 + c * 256 + t) * 4;
        const int ids[4] = {v[c].x, v[c].y, v[c].z, v[c].w};
#pragma unroll
        for (int j = 0; j < 4; j++) {
            if (pix0 + j != m1[ids[j]]) atomicMin(&m2[ids[j]], pix0 + j);
        }
    }
    __syncthreads();

    if (t < KIDS) part[blockIdx.x * KIDS + t] = make_int2(m1[t], m2[t]);
}

// One block per instance id (128 threads). Wave 0 picks the random negative in
// parallel; both waves butterfly-merge the 256 (m1,m2) partials; last block to
// finish (device-scope ticket) computes the final mean. No k_final launch.
__global__ void k_triplet(const float* __restrict__ sem,
                          const int* __restrict__ mask,
                          const int2* __restrict__ part,
                          float* g_total, int* g_cnt, int* g_done,
                          float* __restrict__ out) {
    const int k = blockIdx.x;
    const int t = threadIdx.x;
    __shared__ int s_neg;
    __shared__ int s_pair[4];        // (lo,hi) from each of the 2 waves
    __shared__ float red_ap[128], red_an[128];

    if (t < 64) {   // wave 0: parallel candidate selection
        int cand = 0, ok = 0;
        if (t < NCANDS) {
            const uint32_t bits = jax_cand_bits((uint32_t)(k * NCANDS + t));
            cand = (int)(bits & (uint32_t)(HW - 1));
            ok = (mask[cand] != k) ? 1 : 0;
        }
        const unsigned long long bal = __ballot(ok);
        const int pick = bal ? (__ffsll(bal) - 1) : 0;  // argmax(all-False)=0
        const int neg = __shfl(cand, pick, 64);
        if (t == 0) s_neg = neg;
    }

    // two-smallest-of-union over SEGB partials: 2 serial + wave butterfly
    int lo = SENTINEL, hi = SENTINEL;
#pragma unroll
    for (int r = 0; r < SEGB / 128; r++) {
        const int2 pq = part[(r * 128 + t) * KIDS + k];
        pmerge(lo, hi, pq.x, pq.y);
    }
#pragma unroll
    for (int off = 32; off > 0; off >>= 1) {
        const int alo = __shfl_xor(lo, off, 64);
        const int ahi = __shfl_xor(hi, off, 64);
        pmerge(lo, hi, alo, ahi);
    }
    if ((t & 63) == 0) { s_pair[(t >> 6) * 2] = lo; s_pair[(t >> 6) * 2 + 1] = hi; }
    __syncthreads();
    int f = s_pair[0], s = s_pair[1];
    { int f2 = s_pair[2], s2 = s_pair[3]; pmerge(f, s, f2, s2); }

    const bool valid = (k != 0) && (s != SENTINEL);
    float ap = 0.0f, an = 0.0f;
    if (valid && t < BCC) {
        const int n = s_neg;
        const size_t row = (size_t)t * (size_t)HW;
        const float a  = sem[row + f];
        const float p  = sem[row + s];
        const float nn = sem[row + n];
        const float d1 = a - p + EPSF;
        const float d2 = a - nn + EPSF;
        ap = d1 * d1;
        an = d2 * d2;
    }
    red_ap[t] = ap; red_an[t] = an;
    __syncthreads();
    for (int off = 64; off > 0; off >>= 1) {
        if (t < off) { red_ap[t] += red_ap[t + off]; red_an[t] += red_an[t + off]; }
        __syncthreads();
    }

    if (t == 0) {
        if (valid) {
            float per = sqrtf(red_ap[0]) - sqrtf(red_an[0]) + MARGINF;
            per = per > 0.0f ? per : 0.0f;
            atomicAdd(g_total, per);
            atomicAdd(g_cnt, 1);
        }
        __threadfence();                       // release accumulators
        const int ticket = atomicAdd(g_done, 1);
        if (ticket == KIDS - 1) {              // last block finalizes
            const float tot = atomicAdd(g_total, 0.0f);   // coherent read
            const int   c   = atomicAdd(g_cnt, 0);
            out[0] = (c > 0) ? (tot / (float)c) : 0.0f;
        }
    }
}

extern "C" void kernel_launch(void* const* d_in, const int* in_sizes, int n_in,
                              void* d_out, int out_size, void* d_ws, size_t ws_size,
                              hipStream_t stream) {
    const float* sem  = (const float*)d_in[0];   // [4,19,1024,1024] f32
    const int*   mask = (const int*)d_in[1];     // [1024,1024] i32
    float* out = (float*)d_out;

    // ws layout: [SEGB*KIDS] int2 partials (128 KB) | g_total f32 | g_cnt | g_done
    int2*  part    = (int2*)d_ws;
    float* g_total = (float*)((char*)d_ws + (size_t)SEGB * KIDS * sizeof(int2));
    int*   g_cnt   = (int*)(g_total + 1);
    int*   g_done  = g_cnt + 1;

    k_seg<<<HW / 4096, 256, 0, stream>>>(mask, part, g_total, g_cnt, g_done);
    k_triplet<<<KIDS, 128, 0, stream>>>(sem, mask, part, g_total, g_cnt, g_done, out);
}